// Round 9
// baseline (2797.819 us; speedup 1.0000x reference)
//
#include <hip/hip_runtime.h>

// StageBlocks: FPS -> ball-query -> conv/BN/max -> 2x InvResMLP on MI355X.
// Discrete decisions (FPS argmax, ball membership) use contract-off f32 to
// match XLA/np rounding bitwise. BN via sufficient statistics.
// R9: FPS FT 512 -> 256 (4 waves, 1/SIMD; NP=16). Wave-count trend
// (16w=2643, 8w=1890) says barriers+skew dominate; fewer waves = cheaper
// barriers + single-vector folds, same per-SIMD slot issue. R8's LDS point
// table, skip-phase-2, direct centroid stores kept. Conv retiled for 256T.

#define BB 4
#define NN 8192
#define MM 2048
#define KK 32
#define CI 64
#define CO 128
#define SG 16  // stat groups for gconv atomics

typedef float vf2 __attribute__((ext_vector_type(2)));

// stats layout (doubles)
#define ST_X 0
#define MO_PS 256
#define MO_PE 272
#define ST1 288                    // 2 x 256
#define ST2A 800                   // 2 x SG x 256
#define ST2B (800 + 2 * SG * 256)  // 2 x 256
#define ST_TOTAL (ST2B + 512)

__device__ __forceinline__ float sq3(float dx, float dy, float dz) {
#pragma clang fp contract(off)
  return dx * dx + dy * dy + dz * dz;  // ((x+y)+z), no FMA: matches XLA/np
}

__device__ __forceinline__ void fin_stats_d(const double* st, float gam,
                                            float bet, double cnt, int ch,
                                            float* sc, float* sh) {
  double mean = st[ch] / cnt;
  double var = st[128 + ch] / cnt - mean * mean;
  if (var < 0) var = 0;
  double s = (double)gam / sqrt(var + 1e-5);
  *sc = (float)s;
  *sh = (float)((double)bet - mean * s);
}

__device__ __forceinline__ void fin_mom_d(const double* mo, const float* Wrow,
                                          float gam, float bet, double cnt,
                                          float* sc, float* sh) {
  double w0 = Wrow[0], w1 = Wrow[1], w2 = Wrow[2];
  double mx = mo[0] / cnt, my = mo[1] / cnt, mz = mo[2] / cnt;
  double sxx = mo[3] / cnt, sxy = mo[4] / cnt, sxz = mo[5] / cnt;
  double syy = mo[6] / cnt, syz = mo[7] / cnt, szz = mo[8] / cnt;
  double mean = w0 * mx + w1 * my + w2 * mz;
  double ey2 = w0 * w0 * sxx + w1 * w1 * syy + w2 * w2 * szz +
               2.0 * (w0 * w1 * sxy + w0 * w2 * sxz + w1 * w2 * syz);
  double var = ey2 - mean * mean;
  if (var < 0) var = 0;
  double s = (double)gam / sqrt(var + 1e-5);
  *sc = (float)s;
  *sh = (float)((double)bet - mean * s);
}

__global__ void k_zero(double* s) {
  int i = blockIdx.x * 256 + threadIdx.x;
  if (i < ST_TOTAL) s[i] = 0.0;
}

// ---------------- DPP helpers ----------------
template <int CTRL>
__device__ __forceinline__ int dpp_i(int v) {
  return __builtin_amdgcn_update_dpp(v, v, CTRL, 0xF, 0xF, false);
}
template <int CTRL>
__device__ __forceinline__ float dpp_f(float v) {
  return __int_as_float(dpp_i<CTRL>(__float_as_int(v)));
}

// ---------------- merged FPS (blocks 0..3) + conv_x (blocks 4..259) -------
#define FT 256
#define NP 16  // float2 pairs per thread = 32 points
#define NW 4   // waves

__global__ __launch_bounds__(FT) void k_fps_conv(
    const float* __restrict__ pos, const float* __restrict__ x,
    const float* __restrict__ W_x, float* __restrict__ cent,
    float* __restrict__ fpre, double* __restrict__ stats) {
  __shared__ alignas(16) float s_wv[NW];
  __shared__ alignas(16) int s_wi[NW];
  __shared__ alignas(16) float s_pts[NN * 3];  // 96 KB point table
  int t = threadIdx.x;
  if (blockIdx.x >= BB) {
    // ---- conv part: 64->128 over BB*NN rows, 256 blocks x 256 threads ----
    int cb = blockIdx.x - BB;
    int o = t & 127, q = t >> 7;  // q in {0,1}, wave-uniform
    float4 w[CI / 4];
    const float4* Wv = (const float4*)(W_x + (size_t)o * CI);
#pragma unroll
    for (int i = 0; i < CI / 4; i++) w[i] = Wv[i];
    int row0 = cb * 128;
    float ssum = 0.f, ssq = 0.f;
    for (int r = 0; r < 128; r += 2) {
      int row = __builtin_amdgcn_readfirstlane(row0 + r + q);
      const float* xr = x + (size_t)row * CI;
      float acc = 0.f;
#pragma unroll
      for (int i = 0; i < CI / 4; i++) {
        float4 a = *(const float4*)(xr + 4 * i);
        acc += a.x * w[i].x + a.y * w[i].y + a.z * w[i].z + a.w * w[i].w;
      }
      fpre[(size_t)row * CO + o] = acc;
      ssum += acc;
      ssq += acc * acc;
    }
    atomicAdd(&stats[ST_X + o], (double)ssum);
    atomicAdd(&stats[ST_X + 128 + o], (double)ssq);
    return;
  }
  // ---- FPS part: two-phase argmax, pk slot loop, LDS coord table ----
  int b = blockIdx.x;
  const float* P = pos + (size_t)b * NN * 3;
  float* C = cent + (size_t)b * MM * 3;
  int lane = t & 63, w = t >> 6;
  // stage all points into LDS (raw copy, 12B-stride float3 layout kept)
  for (int i = t; i < (NN * 3) / 4; i += FT) {
    ((float4*)s_pts)[i] = ((const float4*)P)[i];
  }
  vf2 px[NP], py[NP], pz[NP], ds[NP];
#pragma unroll
  for (int s = 0; s < NP; s++) {
    int ia = (2 * s) * FT + t;
    int ib = ia + FT;
    px[s] = (vf2){P[ia * 3 + 0], P[ib * 3 + 0]};
    py[s] = (vf2){P[ia * 3 + 1], P[ib * 3 + 1]};
    pz[s] = (vf2){P[ia * 3 + 2], P[ib * 3 + 2]};
    ds[s] = (vf2){1e10f, 1e10f};
  }
  float lx = P[0], ly = P[1], lz = P[2];
  if (t == 0) {
    C[0] = lx;
    C[1] = ly;
    C[2] = lz;
  }
  __syncthreads();  // table ready
  for (int m = 1; m < MM; m++) {
    // phase 1: packed distance update + value max
    vf2 l2x = (vf2){lx, lx}, l2y = (vf2){ly, ly}, l2z = (vf2){lz, lz};
    vf2 bmax = (vf2){-1.0f, -1.0f};
    {
#pragma clang fp contract(off)
#pragma unroll
      for (int s = 0; s < NP; s++) {
        vf2 dx = px[s] - l2x;
        vf2 dy = py[s] - l2y;
        vf2 dz = pz[s] - l2z;
        vf2 d2 = dx * dx + dy * dy + dz * dz;  // per-lane IEEE, no FMA
        vf2 nd = __builtin_elementwise_min(ds[s], d2);
        ds[s] = nd;
        bmax = __builtin_elementwise_max(bmax, nd);
      }
    }
    float bv = fmaxf(bmax.x, bmax.y);
    bv = fmaxf(bv, dpp_f<0x111>(bv));
    bv = fmaxf(bv, dpp_f<0x112>(bv));
    bv = fmaxf(bv, dpp_f<0x114>(bv));
    bv = fmaxf(bv, dpp_f<0x118>(bv));
    bv = fmaxf(bv, dpp_f<0x142>(bv));
    bv = fmaxf(bv, dpp_f<0x143>(bv));
    if (lane == 63) s_wv[w] = bv;
    float gw63 =
        __int_as_float(__builtin_amdgcn_readlane(__float_as_int(bv), 63));
    __syncthreads();
    float4 va = ((const float4*)s_wv)[0];
    float gmax = fmaxf(fmaxf(va.x, va.y), fmaxf(va.z, va.w));
    // phase 2: smallest index attaining gmax (numpy argmax tie-break).
    // Waves with wave-max < gmax cannot contain it: ds <= bv < gmax.
    int bi = 0x7fffffff;
    if (gw63 == gmax) {
#pragma unroll
      for (int s = 0; s < NP; s++) {
        int ia = (2 * s) * FT + t;
        int ib2 = ia + FT;
        bi = (ds[s].x == gmax) ? (ia < bi ? ia : bi) : bi;
        bi = (ds[s].y == gmax) ? (ib2 < bi ? ib2 : bi) : bi;
      }
      int u;
      u = dpp_i<0x111>(bi); bi = u < bi ? u : bi;
      u = dpp_i<0x112>(bi); bi = u < bi ? u : bi;
      u = dpp_i<0x114>(bi); bi = u < bi ? u : bi;
      u = dpp_i<0x118>(bi); bi = u < bi ? u : bi;
      u = dpp_i<0x142>(bi); bi = u < bi ? u : bi;
      u = dpp_i<0x143>(bi); bi = u < bi ? u : bi;
    }
    if (lane == 63) s_wi[w] = bi;
    __syncthreads();
    int4 ia4 = ((const int4*)s_wi)[0];
    int g0 = ia4.x < ia4.y ? ia4.x : ia4.y;
    int g2 = ia4.z < ia4.w ? ia4.z : ia4.w;
    int gidx = g0 < g2 ? g0 : g2;
    // winner coords from LDS table
    lx = s_pts[gidx * 3 + 0];
    ly = s_pts[gidx * 3 + 1];
    lz = s_pts[gidx * 3 + 2];
    if (t == 0) {
      C[m * 3 + 0] = lx;
      C[m * 3 + 1] = ly;
      C[m * 3 + 2] = lz;
    }
  }
}

// ---------------- both ball queries in one kernel ----------------
__global__ __launch_bounds__(256) void k_bq2(const float* __restrict__ pos,
                                             const float* __restrict__ cent,
                                             int* __restrict__ sel1,
                                             int* __restrict__ sel2,
                                             double* __restrict__ stats) {
  int lane = threadIdx.x & 63, w = threadIdx.x >> 6;
  const float* pts;
  int npts, pair;
  float rsq, inv_r;
  int* sel;
  double* mom;
  int half = (BB * MM) / 4;
  if (blockIdx.x < half) {
    pts = pos; npts = NN; rsq = 0.01f; inv_r = 10.0f;
    sel = sel1; mom = stats + MO_PS;
    pair = blockIdx.x * 4 + w;
  } else {
    pts = cent; npts = MM; rsq = 0.04f; inv_r = 5.0f;
    sel = sel2; mom = stats + MO_PE;
    pair = (blockIdx.x - half) * 4 + w;
  }
  int b = pair / MM;
  const float* P = pts + (size_t)b * npts * 3;
  const float* C = cent + (size_t)pair * 3;
  float cx = C[0], cy = C[1], cz = C[2];
  __shared__ int s_sel[4][KK];
  __shared__ float s_mom[4][9];
  int cnt = 0;
  int nch = npts >> 6;
  for (int ch = 0; ch < nch; ch++) {
    int i = (ch << 6) + lane;
    float d2 = sq3(P[i * 3 + 0] - cx, P[i * 3 + 1] - cy, P[i * 3 + 2] - cz);
    bool hit = d2 < rsq;
    unsigned long long mk = __ballot(hit);
    if (mk) {
      int pre = __popcll(mk & ((1ull << lane) - 1ull));
      int k = cnt + pre;
      if (hit && k < KK) s_sel[w][k] = i;
      cnt += __popcll(mk);
      if (cnt >= KK) break;
    }
  }
  int total = cnt < KK ? cnt : KK;
  int myidx = 0;
  if (lane < KK) {
    int v = (lane < total) ? s_sel[w][lane] : s_sel[w][0];
    sel[(size_t)pair * KK + lane] = v;
    myidx = v;
  }
  float gx = 0.f, gy = 0.f, gz = 0.f;
  if (lane < KK) {
    gx = (P[myidx * 3 + 0] - cx) * inv_r;
    gy = (P[myidx * 3 + 1] - cy) * inv_r;
    gz = (P[myidx * 3 + 2] - cz) * inv_r;
  }
  float v9[9] = {gx, gy, gz, gx * gx, gx * gy, gx * gz, gy * gy, gy * gz, gz * gz};
#pragma unroll
  for (int j = 0; j < 9; j++) {
#pragma unroll
    for (int off = 32; off > 0; off >>= 1) v9[j] += __shfl_xor(v9[j], off);
  }
  if (lane == 0) {
#pragma unroll
    for (int j = 0; j < 9; j++) s_mom[w][j] = v9[j];
  }
  __syncthreads();
  if (threadIdx.x < 9) {
    double a = (double)s_mom[0][threadIdx.x] + s_mom[1][threadIdx.x] +
               s_mom[2][threadIdx.x] + s_mom[3][threadIdx.x];
    atomicAdd(&mom[threadIdx.x], a);
  }
}

// ---------------- stage-1 aggregation (fin folded in prologue) ----------
__global__ __launch_bounds__(128) void k_xf(
    const float* __restrict__ pos, const float* __restrict__ cent,
    const int* __restrict__ sel1, const float* __restrict__ fpre,
    const float* __restrict__ Wps, const float* __restrict__ g_ps,
    const float* __restrict__ b_ps, const float* __restrict__ g_x,
    const float* __restrict__ b_x, const double* __restrict__ stats,
    float* __restrict__ xf) {
  int pair = blockIdx.x;
  int b = pair >> 11;
  int o = threadIdx.x;
  float sx, hx, sp, hp;
  fin_stats_d(stats + ST_X, g_x[o], b_x[o], (double)(BB * NN), o, &sx, &hx);
  fin_mom_d(stats + MO_PS, Wps + o * 3, g_ps[o], b_ps[o],
            (double)(BB * MM * KK), &sp, &hp);
  float w0 = Wps[o * 3 + 0], w1 = Wps[o * 3 + 1], w2 = Wps[o * 3 + 2];
  const float* C = cent + (size_t)pair * 3;
  float cx = C[0], cy = C[1], cz = C[2];
  const float* P = pos + (size_t)b * NN * 3;
  const float* F = fpre + (size_t)b * NN * CO;
  __shared__ int s_idx[KK];
  if (o < KK) s_idx[o] = sel1[(size_t)pair * KK + o];
  __syncthreads();
  float acc = -1e30f;
#pragma unroll 4
  for (int k = 0; k < KK; k++) {
    int idx = __builtin_amdgcn_readfirstlane(s_idx[k]);
    float gx = (P[idx * 3 + 0] - cx) * 10.0f;
    float gy = (P[idx * 3 + 1] - cy) * 10.0f;
    float gz = (P[idx * 3 + 2] - cz) * 10.0f;
    float y = fmaxf((w0 * gx + w1 * gy + w2 * gz) * sp + hp, 0.f);
    float f = fmaxf(F[(size_t)idx * CO + o] * sx + hx, 0.f);
    float v = y + f;
    acc = v > acc ? v : acc;
  }
  xf[(size_t)pair * CO + o] = acc;
}

// ---------------- plain pointwise conv CO->CO + stats ----------------
__global__ __launch_bounds__(256) void k_conv_plain(
    const float* __restrict__ in, const float* __restrict__ W,
    float* __restrict__ out, double* __restrict__ stats, int rows_per_block) {
  int o = threadIdx.x & 127, half = threadIdx.x >> 7;
  float4 w[CO / 4];
  const float4* Wv = (const float4*)(W + (size_t)o * CO);
#pragma unroll
  for (int i = 0; i < CO / 4; i++) w[i] = Wv[i];
  int row0 = blockIdx.x * rows_per_block;
  float ssum = 0.f, ssq = 0.f;
  for (int r = 0; r < rows_per_block; r += 2) {
    int row = __builtin_amdgcn_readfirstlane(row0 + r + half);
    const float* xr = in + (size_t)row * CO;
    float acc = 0.f;
#pragma unroll
    for (int i = 0; i < CO / 4; i++) {
      float4 a = *(const float4*)(xr + 4 * i);
      acc += a.x * w[i].x + a.y * w[i].y + a.z * w[i].z + a.w * w[i].w;
    }
    out[(size_t)row * CO + o] = acc;
    ssum += acc;
    ssq += acc * acc;
  }
  atomicAdd(&stats[o], (double)ssum);
  atomicAdd(&stats[128 + o], (double)ssq);
}

// ---------------- conv with relu(bn(in)) input, scales from grouped stats -
__global__ __launch_bounds__(256) void k_conv_bnin(
    const float* __restrict__ in, const float* __restrict__ W,
    const double* __restrict__ st_grp, const float* __restrict__ gam,
    const float* __restrict__ bet, float* __restrict__ out,
    double* __restrict__ stats, int rows_per_block) {
  __shared__ float s_sc[128], s_sh[128];
  int t = threadIdx.x;
  if (t < 128) {
    double sum = 0, ssq2 = 0;
#pragma unroll
    for (int g = 0; g < SG; g++) {
      sum += st_grp[g * 256 + t];
      ssq2 += st_grp[g * 256 + 128 + t];
    }
    double cnt = (double)(BB * MM);
    double mean = sum / cnt;
    double var = ssq2 / cnt - mean * mean;
    if (var < 0) var = 0;
    double s = (double)gam[t] / sqrt(var + 1e-5);
    s_sc[t] = (float)s;
    s_sh[t] = (float)((double)bet[t] - mean * s);
  }
  __syncthreads();
  int o = t & 127, half = t >> 7;
  float4 w[CO / 4];
  const float4* Wv = (const float4*)(W + (size_t)o * CO);
#pragma unroll
  for (int i = 0; i < CO / 4; i++) w[i] = Wv[i];
  int row0 = blockIdx.x * rows_per_block;
  float ssum = 0.f, ssq = 0.f;
  for (int r = 0; r < rows_per_block; r += 2) {
    int row = __builtin_amdgcn_readfirstlane(row0 + r + half);
    const float* xr = in + (size_t)row * CO;
    float acc = 0.f;
#pragma unroll
    for (int i = 0; i < CO / 4; i++) {
      float4 a = *(const float4*)(xr + 4 * i);
      a.x = fmaxf(a.x * s_sc[4 * i + 0] + s_sh[4 * i + 0], 0.f);
      a.y = fmaxf(a.y * s_sc[4 * i + 1] + s_sh[4 * i + 1], 0.f);
      a.z = fmaxf(a.z * s_sc[4 * i + 2] + s_sh[4 * i + 2], 0.f);
      a.w = fmaxf(a.w * s_sc[4 * i + 3] + s_sh[4 * i + 3], 0.f);
      acc += a.x * w[i].x + a.y * w[i].y + a.z * w[i].z + a.w * w[i].w;
    }
    out[(size_t)row * CO + o] = acc;
    ssum += acc;
    ssq += acc * acc;
  }
  atomicAdd(&stats[o], (double)ssum);
  atomicAdd(&stats[128 + o], (double)ssq);
}

// ---------------- conv1 of block 1 with resid-of-block-0 fused input -----
__global__ __launch_bounds__(256) void k_conv_resid(
    const float* __restrict__ y1prev, const float* __restrict__ y2bprev,
    const double* __restrict__ st1p, const float* __restrict__ g1p,
    const float* __restrict__ b1p, const double* __restrict__ st2bp,
    const float* __restrict__ g2bp, const float* __restrict__ b2bp,
    const float* __restrict__ W, float* __restrict__ y1out,
    double* __restrict__ stats, int rows_per_block) {
  __shared__ float s_s1[128], s_h1[128], s_s2[128], s_h2[128];
  int t = threadIdx.x;
  if (t < 128) {
    fin_stats_d(st1p, g1p[t], b1p[t], (double)(BB * MM), t, &s_s1[t], &s_h1[t]);
    fin_stats_d(st2bp, g2bp[t], b2bp[t], (double)(BB * MM), t, &s_s2[t],
                &s_h2[t]);
  }
  __syncthreads();
  int o = t & 127, half = t >> 7;
  float4 w[CO / 4];
  const float4* Wv = (const float4*)(W + (size_t)o * CO);
#pragma unroll
  for (int i = 0; i < CO / 4; i++) w[i] = Wv[i];
  int row0 = blockIdx.x * rows_per_block;
  float ssum = 0.f, ssq = 0.f;
  for (int r = 0; r < rows_per_block; r += 2) {
    int row = __builtin_amdgcn_readfirstlane(row0 + r + half);
    const float* ar = y1prev + (size_t)row * CO;
    const float* br = y2bprev + (size_t)row * CO;
    float acc = 0.f;
#pragma unroll
    for (int i = 0; i < CO / 4; i++) {
      float4 a = *(const float4*)(ar + 4 * i);
      float4 bb = *(const float4*)(br + 4 * i);
      float x0 = fmaxf(fmaxf(a.x * s_s1[4 * i + 0] + s_h1[4 * i + 0], 0.f) +
                           (bb.x * s_s2[4 * i + 0] + s_h2[4 * i + 0]), 0.f);
      float x1 = fmaxf(fmaxf(a.y * s_s1[4 * i + 1] + s_h1[4 * i + 1], 0.f) +
                           (bb.y * s_s2[4 * i + 1] + s_h2[4 * i + 1]), 0.f);
      float x2 = fmaxf(fmaxf(a.z * s_s1[4 * i + 2] + s_h1[4 * i + 2], 0.f) +
                           (bb.z * s_s2[4 * i + 2] + s_h2[4 * i + 2]), 0.f);
      float x3 = fmaxf(fmaxf(a.w * s_s1[4 * i + 3] + s_h1[4 * i + 3], 0.f) +
                           (bb.w * s_s2[4 * i + 3] + s_h2[4 * i + 3]), 0.f);
      acc += x0 * w[i].x + x1 * w[i].y + x2 * w[i].z + x3 * w[i].w;
    }
    y1out[(size_t)row * CO + o] = acc;
    ssum += acc;
    ssq += acc * acc;
  }
  atomicAdd(&stats[o], (double)ssum);
  atomicAdd(&stats[128 + o], (double)ssq);
}

// ---------------- fused: g = max_k(relu(bn1(y1[sel2])) + pe); y2a = W2a*g -
__global__ __launch_bounds__(128) void k_gconv(
    const float* __restrict__ cent, const int* __restrict__ sel2,
    const float* __restrict__ y1in, const double* __restrict__ st1,
    const float* __restrict__ g1v, const float* __restrict__ b1v,
    const double* __restrict__ mo_pe, const float* __restrict__ Wpe,
    const float* __restrict__ gpe, const float* __restrict__ bpe,
    const float* __restrict__ W2a, float* __restrict__ y2a,
    double* __restrict__ st2a) {
  int pair = blockIdx.x;
  int b = pair >> 11;
  int o = threadIdx.x;
  float s1, h1, se, he;
  fin_stats_d(st1, g1v[o], b1v[o], (double)(BB * MM), o, &s1, &h1);
  fin_mom_d(mo_pe, Wpe + o * 3, gpe[o], bpe[o], (double)(BB * MM * KK), &se,
            &he);
  float w0 = Wpe[o * 3 + 0], w1 = Wpe[o * 3 + 1], w2 = Wpe[o * 3 + 2];
  const float* C = cent + (size_t)pair * 3;
  float cx = C[0], cy = C[1], cz = C[2];
  const float* CB = cent + (size_t)b * MM * 3;
  const float* Y = y1in + (size_t)b * MM * CO;
  __shared__ int s_idx[KK];
  __shared__ float s_g[128];
  if (o < KK) s_idx[o] = sel2[(size_t)pair * KK + o];
  __syncthreads();
  float acc = -1e30f;
#pragma unroll 4
  for (int k = 0; k < KK; k++) {
    int idx = __builtin_amdgcn_readfirstlane(s_idx[k]);
    float gx = (CB[idx * 3 + 0] - cx) * 5.0f;
    float gy = (CB[idx * 3 + 1] - cy) * 5.0f;
    float gz = (CB[idx * 3 + 2] - cz) * 5.0f;
    float pe = fmaxf((w0 * gx + w1 * gy + w2 * gz) * se + he, 0.f);
    float f = fmaxf(Y[(size_t)idx * CO + o] * s1 + h1, 0.f);
    float v = pe + f;
    acc = v > acc ? v : acc;
  }
  s_g[o] = acc;
  __syncthreads();
  const float4* Wv = (const float4*)(W2a + (size_t)o * CO);
  const float4* gv = (const float4*)s_g;
  float dot = 0.f;
#pragma unroll
  for (int i = 0; i < CO / 4; i++) {
    float4 a = gv[i];
    float4 ww = Wv[i];
    dot += a.x * ww.x + a.y * ww.y + a.z * ww.z + a.w * ww.w;
  }
  y2a[(size_t)pair * CO + o] = dot;
  int grp = pair & (SG - 1);
  atomicAdd(&st2a[grp * 256 + o], (double)dot);
  atomicAdd(&st2a[grp * 256 + 128 + o], (double)(dot * dot));
}

// ---------------- final residual (fin folded per-thread) ----------------
__global__ __launch_bounds__(256) void k_resid_fin(
    const float* __restrict__ y1b, const double* __restrict__ st1,
    const float* __restrict__ g1v, const float* __restrict__ b1v,
    const float* __restrict__ y2b, const double* __restrict__ st2b,
    const float* __restrict__ g2bv, const float* __restrict__ b2bv,
    float* __restrict__ xf) {
  int i = blockIdx.x * 256 + threadIdx.x;
  int o = i & 127;
  float s1, h1, s2, h2;
  fin_stats_d(st1, g1v[o], b1v[o], (double)(BB * MM), o, &s1, &h1);
  fin_stats_d(st2b, g2bv[o], b2bv[o], (double)(BB * MM), o, &s2, &h2);
  float f = fmaxf(y1b[i] * s1 + h1, 0.f);
  float v = y2b[i] * s2 + h2;
  xf[i] = fmaxf(f + v, 0.f);
}

extern "C" void kernel_launch(void* const* d_in, const int* in_sizes, int n_in,
                              void* d_out, int out_size, void* d_ws,
                              size_t ws_size, hipStream_t stream) {
  const float* pos = (const float*)d_in[0];
  const float* x = (const float*)d_in[1];
  const float* W_x = (const float*)d_in[2];
  const float* g_x = (const float*)d_in[3];
  const float* b_x = (const float*)d_in[4];
  const float* W_ps = (const float*)d_in[5];
  const float* g_ps = (const float*)d_in[6];
  const float* b_ps = (const float*)d_in[7];
  const float* W_pe = (const float*)d_in[8];
  const float* g_pe = (const float*)d_in[9];
  const float* b_pe = (const float*)d_in[10];
  const float* W1 = (const float*)d_in[11];
  const float* g1 = (const float*)d_in[12];
  const float* b1 = (const float*)d_in[13];
  const float* W2a = (const float*)d_in[14];
  const float* g2a = (const float*)d_in[15];
  const float* b2a = (const float*)d_in[16];
  const float* W2b = (const float*)d_in[17];
  const float* g2b = (const float*)d_in[18];
  const float* b2b = (const float*)d_in[19];

  float* cent = (float*)d_out;             // (B,M,3)
  float* xf = cent + (size_t)BB * MM * 3;  // (B,M,128)

  char* p = (char*)d_ws;
  double* stats = (double*)p; p += (size_t)ST_TOTAL * sizeof(double);
  int* sel1 = (int*)p;        p += (size_t)BB * MM * KK * sizeof(int);
  int* sel2 = (int*)p;        p += (size_t)BB * MM * KK * sizeof(int);
  float* fpre = (float*)p;    p += (size_t)BB * NN * CO * sizeof(float);
  float* y1a = (float*)p;     p += (size_t)BB * MM * CO * sizeof(float);
  float* y1b = (float*)p;     p += (size_t)BB * MM * CO * sizeof(float);
  float* y2a = (float*)p;     p += (size_t)BB * MM * CO * sizeof(float);
  float* y2b = (float*)p;     p += (size_t)BB * MM * CO * sizeof(float);

  k_zero<<<(ST_TOTAL + 255) / 256, 256, 0, stream>>>(stats);
  k_fps_conv<<<BB + 256, FT, 0, stream>>>(pos, x, W_x, cent, fpre, stats);
  k_bq2<<<(BB * MM) / 2, 256, 0, stream>>>(pos, cent, sel1, sel2, stats);
  k_xf<<<BB * MM, 128, 0, stream>>>(pos, cent, sel1, fpre, W_ps, g_ps, b_ps,
                                    g_x, b_x, stats, xf);
  // ---- InvResMLP block 0 ----
  k_conv_plain<<<128, 256, 0, stream>>>(xf, W1, y1a, stats + ST1, 64);
  k_gconv<<<BB * MM, 128, 0, stream>>>(cent, sel2, y1a, stats + ST1, g1, b1,
                                       stats + MO_PE, W_pe, g_pe, b_pe, W2a,
                                       y2a, stats + ST2A);
  k_conv_bnin<<<128, 256, 0, stream>>>(y2a, W2b, stats + ST2A, g2a, b2a, y2b,
                                       stats + ST2B, 64);
  // ---- InvResMLP block 1 (resid of block 0 fused into conv1) ----
  k_conv_resid<<<128, 256, 0, stream>>>(
      y1a, y2b, stats + ST1, g1, b1, stats + ST2B, g2b, b2b, W1 + CO * CO, y1b,
      stats + ST1 + 256, 64);
  k_gconv<<<BB * MM, 128, 0, stream>>>(cent, sel2, y1b, stats + ST1 + 256,
                                       g1 + 128, b1 + 128, stats + MO_PE, W_pe,
                                       g_pe, b_pe, W2a + CO * CO, y2a,
                                       stats + ST2A + SG * 256);
  k_conv_bnin<<<128, 256, 0, stream>>>(y2a, W2b + CO * CO,
                                       stats + ST2A + SG * 256, g2a + 128,
                                       b2a + 128, y2b, stats + ST2B + 256, 64);
  k_resid_fin<<<(BB * MM * CO) / 256, 256, 0, stream>>>(
      y1b, stats + ST1 + 256, g1 + 128, b1 + 128, y2b, stats + ST2B + 256,
      g2b + 128, b2b + 128, xf);
}

// Round 10
// 2679.345 us; speedup vs baseline: 1.0442x; 1.0442x over previous
//
#include <hip/hip_runtime.h>

// StageBlocks: FPS -> ball-query -> conv/BN/max -> 2x InvResMLP on MI355X.
// Discrete decisions (FPS argmax, ball membership) use contract-off f32 to
// match XLA/np rounding bitwise. BN via sufficient statistics.
// R10: FPS = R8 exact (FT=512 optimum: 4w=1993, 8w=1890, 16w=2643 measured).
// Tail: conv1 fused into k_xf (xf intermediate never materialized; st1
// SG-grouped), k_bq2 scans 256 points/iter (4 ballots), k_zero replaced by
// hipMemsetAsync.

#define BB 4
#define NN 8192
#define MM 2048
#define KK 32
#define CI 64
#define CO 128
#define SG 16  // stat groups for high-block-count atomics

typedef float vf2 __attribute__((ext_vector_type(2)));

// stats layout (doubles)
#define ST_X 0
#define MO_PS 256
#define MO_PE 272
#define ST1 288                     // 2 x SG x 256 (block0, block1)
#define ST2A (288 + 2 * SG * 256)   // 2 x SG x 256
#define ST2B (ST2A + 2 * SG * 256)  // 2 x 256
#define ST_TOTAL (ST2B + 512)

__device__ __forceinline__ float sq3(float dx, float dy, float dz) {
#pragma clang fp contract(off)
  return dx * dx + dy * dy + dz * dz;  // ((x+y)+z), no FMA: matches XLA/np
}

__device__ __forceinline__ void fin_stats_d(const double* st, float gam,
                                            float bet, double cnt, int ch,
                                            float* sc, float* sh) {
  double mean = st[ch] / cnt;
  double var = st[128 + ch] / cnt - mean * mean;
  if (var < 0) var = 0;
  double s = (double)gam / sqrt(var + 1e-5);
  *sc = (float)s;
  *sh = (float)((double)bet - mean * s);
}

// grouped (SG partial sums) variant
__device__ __forceinline__ void fin_grp_d(const double* st, float gam,
                                          float bet, double cnt, int ch,
                                          float* sc, float* sh) {
  double sum = 0, ssq = 0;
#pragma unroll
  for (int g = 0; g < SG; g++) {
    sum += st[g * 256 + ch];
    ssq += st[g * 256 + 128 + ch];
  }
  double mean = sum / cnt;
  double var = ssq / cnt - mean * mean;
  if (var < 0) var = 0;
  double s = (double)gam / sqrt(var + 1e-5);
  *sc = (float)s;
  *sh = (float)((double)bet - mean * s);
}

__device__ __forceinline__ void fin_mom_d(const double* mo, const float* Wrow,
                                          float gam, float bet, double cnt,
                                          float* sc, float* sh) {
  double w0 = Wrow[0], w1 = Wrow[1], w2 = Wrow[2];
  double mx = mo[0] / cnt, my = mo[1] / cnt, mz = mo[2] / cnt;
  double sxx = mo[3] / cnt, sxy = mo[4] / cnt, sxz = mo[5] / cnt;
  double syy = mo[6] / cnt, syz = mo[7] / cnt, szz = mo[8] / cnt;
  double mean = w0 * mx + w1 * my + w2 * mz;
  double ey2 = w0 * w0 * sxx + w1 * w1 * syy + w2 * w2 * szz +
               2.0 * (w0 * w1 * sxy + w0 * w2 * sxz + w1 * w2 * syz);
  double var = ey2 - mean * mean;
  if (var < 0) var = 0;
  double s = (double)gam / sqrt(var + 1e-5);
  *sc = (float)s;
  *sh = (float)((double)bet - mean * s);
}

// ---------------- DPP helpers ----------------
template <int CTRL>
__device__ __forceinline__ int dpp_i(int v) {
  return __builtin_amdgcn_update_dpp(v, v, CTRL, 0xF, 0xF, false);
}
template <int CTRL>
__device__ __forceinline__ float dpp_f(float v) {
  return __int_as_float(dpp_i<CTRL>(__float_as_int(v)));
}

// ---------------- merged FPS (blocks 0..3) + conv_x (blocks 4..259) -------
#define FT 512
#define NP 8  // float2 pairs per thread = 16 points
#define NW 8

__global__ __launch_bounds__(FT) void k_fps_conv(
    const float* __restrict__ pos, const float* __restrict__ x,
    const float* __restrict__ W_x, float* __restrict__ cent,
    float* __restrict__ fpre, double* __restrict__ stats) {
  __shared__ alignas(16) float s_wv[NW];
  __shared__ alignas(16) int s_wi[NW];
  __shared__ alignas(16) float s_pts[NN * 3];  // 96 KB point table
  int t = threadIdx.x;
  if (blockIdx.x >= BB) {
    // ---- conv part: 64->128 over BB*NN rows, 256 blocks x 512 threads ----
    int cb = blockIdx.x - BB;
    int o = t & 127, q = t >> 7;  // q wave-uniform
    float4 w[CI / 4];
    const float4* Wv = (const float4*)(W_x + (size_t)o * CI);
#pragma unroll
    for (int i = 0; i < CI / 4; i++) w[i] = Wv[i];
    int row0 = cb * 128;
    float ssum = 0.f, ssq = 0.f;
    for (int r = 0; r < 128; r += 4) {
      int row = __builtin_amdgcn_readfirstlane(row0 + r + q);
      const float* xr = x + (size_t)row * CI;
      float acc = 0.f;
#pragma unroll
      for (int i = 0; i < CI / 4; i++) {
        float4 a = *(const float4*)(xr + 4 * i);
        acc += a.x * w[i].x + a.y * w[i].y + a.z * w[i].z + a.w * w[i].w;
      }
      fpre[(size_t)row * CO + o] = acc;
      ssum += acc;
      ssq += acc * acc;
    }
    atomicAdd(&stats[ST_X + o], (double)ssum);
    atomicAdd(&stats[ST_X + 128 + o], (double)ssq);
    return;
  }
  // ---- FPS part: two-phase argmax, pk slot loop, LDS coord table ----
  int b = blockIdx.x;
  const float* P = pos + (size_t)b * NN * 3;
  float* C = cent + (size_t)b * MM * 3;
  int lane = t & 63, w = t >> 6;
  for (int i = t; i < (NN * 3) / 4; i += FT) {
    ((float4*)s_pts)[i] = ((const float4*)P)[i];
  }
  vf2 px[NP], py[NP], pz[NP], ds[NP];
#pragma unroll
  for (int s = 0; s < NP; s++) {
    int ia = (2 * s) * FT + t;
    int ib = ia + FT;
    px[s] = (vf2){P[ia * 3 + 0], P[ib * 3 + 0]};
    py[s] = (vf2){P[ia * 3 + 1], P[ib * 3 + 1]};
    pz[s] = (vf2){P[ia * 3 + 2], P[ib * 3 + 2]};
    ds[s] = (vf2){1e10f, 1e10f};
  }
  float lx = P[0], ly = P[1], lz = P[2];
  if (t == 0) {
    C[0] = lx;
    C[1] = ly;
    C[2] = lz;
  }
  __syncthreads();  // table ready
  for (int m = 1; m < MM; m++) {
    vf2 l2x = (vf2){lx, lx}, l2y = (vf2){ly, ly}, l2z = (vf2){lz, lz};
    vf2 bmax = (vf2){-1.0f, -1.0f};
    {
#pragma clang fp contract(off)
#pragma unroll
      for (int s = 0; s < NP; s++) {
        vf2 dx = px[s] - l2x;
        vf2 dy = py[s] - l2y;
        vf2 dz = pz[s] - l2z;
        vf2 d2 = dx * dx + dy * dy + dz * dz;  // per-lane IEEE, no FMA
        vf2 nd = __builtin_elementwise_min(ds[s], d2);
        ds[s] = nd;
        bmax = __builtin_elementwise_max(bmax, nd);
      }
    }
    float bv = fmaxf(bmax.x, bmax.y);
    bv = fmaxf(bv, dpp_f<0x111>(bv));
    bv = fmaxf(bv, dpp_f<0x112>(bv));
    bv = fmaxf(bv, dpp_f<0x114>(bv));
    bv = fmaxf(bv, dpp_f<0x118>(bv));
    bv = fmaxf(bv, dpp_f<0x142>(bv));
    bv = fmaxf(bv, dpp_f<0x143>(bv));
    if (lane == 63) s_wv[w] = bv;
    float gw63 =
        __int_as_float(__builtin_amdgcn_readlane(__float_as_int(bv), 63));
    __syncthreads();
    float4 va = ((const float4*)s_wv)[0];
    float4 vb = ((const float4*)s_wv)[1];
    float gmax = fmaxf(fmaxf(fmaxf(va.x, va.y), fmaxf(va.z, va.w)),
                       fmaxf(fmaxf(vb.x, vb.y), fmaxf(vb.z, vb.w)));
    int bi = 0x7fffffff;
    if (gw63 == gmax) {  // non-winner waves: ds <= bv < gmax, skip scan
#pragma unroll
      for (int s = 0; s < NP; s++) {
        int ia = (2 * s) * FT + t;
        int ib2 = ia + FT;
        bi = (ds[s].x == gmax) ? (ia < bi ? ia : bi) : bi;
        bi = (ds[s].y == gmax) ? (ib2 < bi ? ib2 : bi) : bi;
      }
      int u;
      u = dpp_i<0x111>(bi); bi = u < bi ? u : bi;
      u = dpp_i<0x112>(bi); bi = u < bi ? u : bi;
      u = dpp_i<0x114>(bi); bi = u < bi ? u : bi;
      u = dpp_i<0x118>(bi); bi = u < bi ? u : bi;
      u = dpp_i<0x142>(bi); bi = u < bi ? u : bi;
      u = dpp_i<0x143>(bi); bi = u < bi ? u : bi;
    }
    if (lane == 63) s_wi[w] = bi;
    __syncthreads();
    int4 ia4 = ((const int4*)s_wi)[0];
    int4 ib4 = ((const int4*)s_wi)[1];
    int g0 = ia4.x < ia4.y ? ia4.x : ia4.y;
    int g1 = ia4.z < ia4.w ? ia4.z : ia4.w;
    int g2 = ib4.x < ib4.y ? ib4.x : ib4.y;
    int g3 = ib4.z < ib4.w ? ib4.z : ib4.w;
    g0 = g0 < g1 ? g0 : g1;
    g2 = g2 < g3 ? g2 : g3;
    int gidx = g0 < g2 ? g0 : g2;
    lx = s_pts[gidx * 3 + 0];
    ly = s_pts[gidx * 3 + 1];
    lz = s_pts[gidx * 3 + 2];
    if (t == 0) {
      C[m * 3 + 0] = lx;
      C[m * 3 + 1] = ly;
      C[m * 3 + 2] = lz;
    }
  }
}

// ---------------- both ball queries in one kernel (4 chunks/iter) --------
__global__ __launch_bounds__(256) void k_bq2(const float* __restrict__ pos,
                                             const float* __restrict__ cent,
                                             int* __restrict__ sel1,
                                             int* __restrict__ sel2,
                                             double* __restrict__ stats) {
  int lane = threadIdx.x & 63, w = threadIdx.x >> 6;
  const float* pts;
  int npts, pair;
  float rsq, inv_r;
  int* sel;
  double* mom;
  int half = (BB * MM) / 4;
  if (blockIdx.x < half) {
    pts = pos; npts = NN; rsq = 0.01f; inv_r = 10.0f;
    sel = sel1; mom = stats + MO_PS;
    pair = blockIdx.x * 4 + w;
  } else {
    pts = cent; npts = MM; rsq = 0.04f; inv_r = 5.0f;
    sel = sel2; mom = stats + MO_PE;
    pair = (blockIdx.x - half) * 4 + w;
  }
  int b = pair / MM;
  const float* P = pts + (size_t)b * npts * 3;
  const float* C = cent + (size_t)pair * 3;
  float cx = C[0], cy = C[1], cz = C[2];
  __shared__ int s_sel[4][KK];
  __shared__ float s_mom[4][9];
  int cnt = 0;
  unsigned long long ltm = (1ull << lane) - 1ull;
  int nit = npts >> 8;  // 256 points per iteration
  for (int ch = 0; ch < nit; ch++) {
    int i0 = (ch << 8) + lane;
    bool h0, h1, h2, h3;
    {
      float a0 = P[i0 * 3 + 0], a1 = P[i0 * 3 + 1], a2 = P[i0 * 3 + 2];
      float b0 = P[(i0 + 64) * 3 + 0], b1 = P[(i0 + 64) * 3 + 1],
            b2 = P[(i0 + 64) * 3 + 2];
      float c0 = P[(i0 + 128) * 3 + 0], c1 = P[(i0 + 128) * 3 + 1],
            c2 = P[(i0 + 128) * 3 + 2];
      float e0 = P[(i0 + 192) * 3 + 0], e1 = P[(i0 + 192) * 3 + 1],
            e2 = P[(i0 + 192) * 3 + 2];
      h0 = sq3(a0 - cx, a1 - cy, a2 - cz) < rsq;
      h1 = sq3(b0 - cx, b1 - cy, b2 - cz) < rsq;
      h2 = sq3(c0 - cx, c1 - cy, c2 - cz) < rsq;
      h3 = sq3(e0 - cx, e1 - cy, e2 - cz) < rsq;
    }
    unsigned long long m0 = __ballot(h0);
    unsigned long long m1 = __ballot(h1);
    unsigned long long m2 = __ballot(h2);
    unsigned long long m3 = __ballot(h3);
    if (m0) {
      int k = cnt + __popcll(m0 & ltm);
      if (h0 && k < KK) s_sel[w][k] = i0;
      cnt += __popcll(m0);
    }
    if (m1) {
      int k = cnt + __popcll(m1 & ltm);
      if (h1 && k < KK) s_sel[w][k] = i0 + 64;
      cnt += __popcll(m1);
    }
    if (m2) {
      int k = cnt + __popcll(m2 & ltm);
      if (h2 && k < KK) s_sel[w][k] = i0 + 128;
      cnt += __popcll(m2);
    }
    if (m3) {
      int k = cnt + __popcll(m3 & ltm);
      if (h3 && k < KK) s_sel[w][k] = i0 + 192;
      cnt += __popcll(m3);
    }
    if (cnt >= KK) break;
  }
  int total = cnt < KK ? cnt : KK;
  int myidx = 0;
  if (lane < KK) {
    int v = (lane < total) ? s_sel[w][lane] : s_sel[w][0];
    sel[(size_t)pair * KK + lane] = v;
    myidx = v;
  }
  float gx = 0.f, gy = 0.f, gz = 0.f;
  if (lane < KK) {
    gx = (P[myidx * 3 + 0] - cx) * inv_r;
    gy = (P[myidx * 3 + 1] - cy) * inv_r;
    gz = (P[myidx * 3 + 2] - cz) * inv_r;
  }
  float v9[9] = {gx, gy, gz, gx * gx, gx * gy, gx * gz, gy * gy, gy * gz, gz * gz};
#pragma unroll
  for (int j = 0; j < 9; j++) {
#pragma unroll
    for (int off = 32; off > 0; off >>= 1) v9[j] += __shfl_xor(v9[j], off);
  }
  if (lane == 0) {
#pragma unroll
    for (int j = 0; j < 9; j++) s_mom[w][j] = v9[j];
  }
  __syncthreads();
  if (threadIdx.x < 9) {
    double a = (double)s_mom[0][threadIdx.x] + s_mom[1][threadIdx.x] +
               s_mom[2][threadIdx.x] + s_mom[3][threadIdx.x];
    atomicAdd(&mom[threadIdx.x], a);
  }
}

// ---------------- fused stage-1 aggregation + conv1(block0) -------------
// xf row (never materialized) -> LDS -> y1a = W1 . xf ; grouped st1 stats.
__global__ __launch_bounds__(128) void k_xf_conv1(
    const float* __restrict__ pos, const float* __restrict__ cent,
    const int* __restrict__ sel1, const float* __restrict__ fpre,
    const float* __restrict__ Wps, const float* __restrict__ g_ps,
    const float* __restrict__ b_ps, const float* __restrict__ g_x,
    const float* __restrict__ b_x, const double* __restrict__ stats,
    const float* __restrict__ W1, float* __restrict__ y1a,
    double* __restrict__ st1out) {
  int pair = blockIdx.x;
  int b = pair >> 11;
  int o = threadIdx.x;
  float sx, hx, sp, hp;
  fin_stats_d(stats + ST_X, g_x[o], b_x[o], (double)(BB * NN), o, &sx, &hx);
  fin_mom_d(stats + MO_PS, Wps + o * 3, g_ps[o], b_ps[o],
            (double)(BB * MM * KK), &sp, &hp);
  float w0 = Wps[o * 3 + 0], w1 = Wps[o * 3 + 1], w2 = Wps[o * 3 + 2];
  const float* C = cent + (size_t)pair * 3;
  float cx = C[0], cy = C[1], cz = C[2];
  const float* P = pos + (size_t)b * NN * 3;
  const float* F = fpre + (size_t)b * NN * CO;
  __shared__ int s_idx[KK];
  __shared__ float s_xf[128];
  if (o < KK) s_idx[o] = sel1[(size_t)pair * KK + o];
  __syncthreads();
  float acc = -1e30f;
#pragma unroll 4
  for (int k = 0; k < KK; k++) {
    int idx = __builtin_amdgcn_readfirstlane(s_idx[k]);
    float gx = (P[idx * 3 + 0] - cx) * 10.0f;
    float gy = (P[idx * 3 + 1] - cy) * 10.0f;
    float gz = (P[idx * 3 + 2] - cz) * 10.0f;
    float y = fmaxf((w0 * gx + w1 * gy + w2 * gz) * sp + hp, 0.f);
    float f = fmaxf(F[(size_t)idx * CO + o] * sx + hx, 0.f);
    float v = y + f;
    acc = v > acc ? v : acc;
  }
  s_xf[o] = acc;
  __syncthreads();
  const float4* Wv = (const float4*)(W1 + (size_t)o * CO);
  const float4* gv = (const float4*)s_xf;
  float dot = 0.f;
#pragma unroll
  for (int i = 0; i < CO / 4; i++) {
    float4 a = gv[i];
    float4 ww = Wv[i];
    dot += a.x * ww.x + a.y * ww.y + a.z * ww.z + a.w * ww.w;
  }
  y1a[(size_t)pair * CO + o] = dot;
  int grp = pair & (SG - 1);
  atomicAdd(&st1out[grp * 256 + o], (double)dot);
  atomicAdd(&st1out[grp * 256 + 128 + o], (double)(dot * dot));
}

// ---------------- conv with relu(bn(in)) input, scales from grouped stats -
__global__ __launch_bounds__(256) void k_conv_bnin(
    const float* __restrict__ in, const float* __restrict__ W,
    const double* __restrict__ st_grp, const float* __restrict__ gam,
    const float* __restrict__ bet, float* __restrict__ out,
    double* __restrict__ stats, int rows_per_block) {
  __shared__ float s_sc[128], s_sh[128];
  int t = threadIdx.x;
  if (t < 128) {
    fin_grp_d(st_grp, gam[t], bet[t], (double)(BB * MM), t, &s_sc[t],
              &s_sh[t]);
  }
  __syncthreads();
  int o = t & 127, half = t >> 7;
  float4 w[CO / 4];
  const float4* Wv = (const float4*)(W + (size_t)o * CO);
#pragma unroll
  for (int i = 0; i < CO / 4; i++) w[i] = Wv[i];
  int row0 = blockIdx.x * rows_per_block;
  float ssum = 0.f, ssq = 0.f;
  for (int r = 0; r < rows_per_block; r += 2) {
    int row = __builtin_amdgcn_readfirstlane(row0 + r + half);
    const float* xr = in + (size_t)row * CO;
    float acc = 0.f;
#pragma unroll
    for (int i = 0; i < CO / 4; i++) {
      float4 a = *(const float4*)(xr + 4 * i);
      a.x = fmaxf(a.x * s_sc[4 * i + 0] + s_sh[4 * i + 0], 0.f);
      a.y = fmaxf(a.y * s_sc[4 * i + 1] + s_sh[4 * i + 1], 0.f);
      a.z = fmaxf(a.z * s_sc[4 * i + 2] + s_sh[4 * i + 2], 0.f);
      a.w = fmaxf(a.w * s_sc[4 * i + 3] + s_sh[4 * i + 3], 0.f);
      acc += a.x * w[i].x + a.y * w[i].y + a.z * w[i].z + a.w * w[i].w;
    }
    out[(size_t)row * CO + o] = acc;
    ssum += acc;
    ssq += acc * acc;
  }
  atomicAdd(&stats[o], (double)ssum);
  atomicAdd(&stats[128 + o], (double)ssq);
}

// ---------------- conv1 of block 1 with resid-of-block-0 fused input -----
__global__ __launch_bounds__(256) void k_conv_resid(
    const float* __restrict__ y1prev, const float* __restrict__ y2bprev,
    const double* __restrict__ st1p, const float* __restrict__ g1p,
    const float* __restrict__ b1p, const double* __restrict__ st2bp,
    const float* __restrict__ g2bp, const float* __restrict__ b2bp,
    const float* __restrict__ W, float* __restrict__ y1out,
    double* __restrict__ stats, int rows_per_block) {
  __shared__ float s_s1[128], s_h1[128], s_s2[128], s_h2[128];
  int t = threadIdx.x;
  if (t < 128) {
    fin_grp_d(st1p, g1p[t], b1p[t], (double)(BB * MM), t, &s_s1[t], &s_h1[t]);
    fin_stats_d(st2bp, g2bp[t], b2bp[t], (double)(BB * MM), t, &s_s2[t],
                &s_h2[t]);
  }
  __syncthreads();
  int o = t & 127, half = t >> 7;
  float4 w[CO / 4];
  const float4* Wv = (const float4*)(W + (size_t)o * CO);
#pragma unroll
  for (int i = 0; i < CO / 4; i++) w[i] = Wv[i];
  int row0 = blockIdx.x * rows_per_block;
  float ssum = 0.f, ssq = 0.f;
  for (int r = 0; r < rows_per_block; r += 2) {
    int row = __builtin_amdgcn_readfirstlane(row0 + r + half);
    const float* ar = y1prev + (size_t)row * CO;
    const float* br = y2bprev + (size_t)row * CO;
    float acc = 0.f;
#pragma unroll
    for (int i = 0; i < CO / 4; i++) {
      float4 a = *(const float4*)(ar + 4 * i);
      float4 bb = *(const float4*)(br + 4 * i);
      float x0 = fmaxf(fmaxf(a.x * s_s1[4 * i + 0] + s_h1[4 * i + 0], 0.f) +
                           (bb.x * s_s2[4 * i + 0] + s_h2[4 * i + 0]), 0.f);
      float x1 = fmaxf(fmaxf(a.y * s_s1[4 * i + 1] + s_h1[4 * i + 1], 0.f) +
                           (bb.y * s_s2[4 * i + 1] + s_h2[4 * i + 1]), 0.f);
      float x2 = fmaxf(fmaxf(a.z * s_s1[4 * i + 2] + s_h1[4 * i + 2], 0.f) +
                           (bb.z * s_s2[4 * i + 2] + s_h2[4 * i + 2]), 0.f);
      float x3 = fmaxf(fmaxf(a.w * s_s1[4 * i + 3] + s_h1[4 * i + 3], 0.f) +
                           (bb.w * s_s2[4 * i + 3] + s_h2[4 * i + 3]), 0.f);
      acc += x0 * w[i].x + x1 * w[i].y + x2 * w[i].z + x3 * w[i].w;
    }
    y1out[(size_t)row * CO + o] = acc;
    ssum += acc;
    ssq += acc * acc;
  }
  int grp = blockIdx.x & (SG - 1);
  atomicAdd(&stats[grp * 256 + o], (double)ssum);
  atomicAdd(&stats[grp * 256 + 128 + o], (double)ssq);
}

// ---------------- fused: g = max_k(relu(bn1(y1[sel2])) + pe); y2a = W2a*g -
__global__ __launch_bounds__(128) void k_gconv(
    const float* __restrict__ cent, const int* __restrict__ sel2,
    const float* __restrict__ y1in, const double* __restrict__ st1,
    const float* __restrict__ g1v, const float* __restrict__ b1v,
    const double* __restrict__ mo_pe, const float* __restrict__ Wpe,
    const float* __restrict__ gpe, const float* __restrict__ bpe,
    const float* __restrict__ W2a, float* __restrict__ y2a,
    double* __restrict__ st2a) {
  int pair = blockIdx.x;
  int b = pair >> 11;
  int o = threadIdx.x;
  float s1, h1, se, he;
  fin_grp_d(st1, g1v[o], b1v[o], (double)(BB * MM), o, &s1, &h1);
  fin_mom_d(mo_pe, Wpe + o * 3, gpe[o], bpe[o], (double)(BB * MM * KK), &se,
            &he);
  float w0 = Wpe[o * 3 + 0], w1 = Wpe[o * 3 + 1], w2 = Wpe[o * 3 + 2];
  const float* C = cent + (size_t)pair * 3;
  float cx = C[0], cy = C[1], cz = C[2];
  const float* CB = cent + (size_t)b * MM * 3;
  const float* Y = y1in + (size_t)b * MM * CO;
  __shared__ int s_idx[KK];
  __shared__ float s_g[128];
  if (o < KK) s_idx[o] = sel2[(size_t)pair * KK + o];
  __syncthreads();
  float acc = -1e30f;
#pragma unroll 4
  for (int k = 0; k < KK; k++) {
    int idx = __builtin_amdgcn_readfirstlane(s_idx[k]);
    float gx = (CB[idx * 3 + 0] - cx) * 5.0f;
    float gy = (CB[idx * 3 + 1] - cy) * 5.0f;
    float gz = (CB[idx * 3 + 2] - cz) * 5.0f;
    float pe = fmaxf((w0 * gx + w1 * gy + w2 * gz) * se + he, 0.f);
    float f = fmaxf(Y[(size_t)idx * CO + o] * s1 + h1, 0.f);
    float v = pe + f;
    acc = v > acc ? v : acc;
  }
  s_g[o] = acc;
  __syncthreads();
  const float4* Wv = (const float4*)(W2a + (size_t)o * CO);
  const float4* gv = (const float4*)s_g;
  float dot = 0.f;
#pragma unroll
  for (int i = 0; i < CO / 4; i++) {
    float4 a = gv[i];
    float4 ww = Wv[i];
    dot += a.x * ww.x + a.y * ww.y + a.z * ww.z + a.w * ww.w;
  }
  y2a[(size_t)pair * CO + o] = dot;
  int grp = pair & (SG - 1);
  atomicAdd(&st2a[grp * 256 + o], (double)dot);
  atomicAdd(&st2a[grp * 256 + 128 + o], (double)(dot * dot));
}

// ---------------- final residual (fin folded per-thread) ----------------
__global__ __launch_bounds__(256) void k_resid_fin(
    const float* __restrict__ y1b, const double* __restrict__ st1,
    const float* __restrict__ g1v, const float* __restrict__ b1v,
    const float* __restrict__ y2b, const double* __restrict__ st2b,
    const float* __restrict__ g2bv, const float* __restrict__ b2bv,
    float* __restrict__ xf) {
  int i = blockIdx.x * 256 + threadIdx.x;
  int o = i & 127;
  float s1, h1, s2, h2;
  fin_grp_d(st1, g1v[o], b1v[o], (double)(BB * MM), o, &s1, &h1);
  fin_stats_d(st2b, g2bv[o], b2bv[o], (double)(BB * MM), o, &s2, &h2);
  float f = fmaxf(y1b[i] * s1 + h1, 0.f);
  float v = y2b[i] * s2 + h2;
  xf[i] = fmaxf(f + v, 0.f);
}

extern "C" void kernel_launch(void* const* d_in, const int* in_sizes, int n_in,
                              void* d_out, int out_size, void* d_ws,
                              size_t ws_size, hipStream_t stream) {
  const float* pos = (const float*)d_in[0];
  const float* x = (const float*)d_in[1];
  const float* W_x = (const float*)d_in[2];
  const float* g_x = (const float*)d_in[3];
  const float* b_x = (const float*)d_in[4];
  const float* W_ps = (const float*)d_in[5];
  const float* g_ps = (const float*)d_in[6];
  const float* b_ps = (const float*)d_in[7];
  const float* W_pe = (const float*)d_in[8];
  const float* g_pe = (const float*)d_in[9];
  const float* b_pe = (const float*)d_in[10];
  const float* W1 = (const float*)d_in[11];
  const float* g1 = (const float*)d_in[12];
  const float* b1 = (const float*)d_in[13];
  const float* W2a = (const float*)d_in[14];
  const float* g2a = (const float*)d_in[15];
  const float* b2a = (const float*)d_in[16];
  const float* W2b = (const float*)d_in[17];
  const float* g2b = (const float*)d_in[18];
  const float* b2b = (const float*)d_in[19];

  float* cent = (float*)d_out;             // (B,M,3)
  float* xf = cent + (size_t)BB * MM * 3;  // (B,M,128)

  char* p = (char*)d_ws;
  double* stats = (double*)p; p += (size_t)ST_TOTAL * sizeof(double);
  int* sel1 = (int*)p;        p += (size_t)BB * MM * KK * sizeof(int);
  int* sel2 = (int*)p;        p += (size_t)BB * MM * KK * sizeof(int);
  float* fpre = (float*)p;    p += (size_t)BB * NN * CO * sizeof(float);
  float* y1a = (float*)p;     p += (size_t)BB * MM * CO * sizeof(float);
  float* y1b = (float*)p;     p += (size_t)BB * MM * CO * sizeof(float);
  float* y2a = (float*)p;     p += (size_t)BB * MM * CO * sizeof(float);
  float* y2b = (float*)p;     p += (size_t)BB * MM * CO * sizeof(float);

  hipMemsetAsync(stats, 0, (size_t)ST_TOTAL * sizeof(double), stream);
  k_fps_conv<<<BB + 256, FT, 0, stream>>>(pos, x, W_x, cent, fpre, stats);
  k_bq2<<<(BB * MM) / 2, 256, 0, stream>>>(pos, cent, sel1, sel2, stats);
  k_xf_conv1<<<BB * MM, 128, 0, stream>>>(pos, cent, sel1, fpre, W_ps, g_ps,
                                          b_ps, g_x, b_x, stats, W1, y1a,
                                          stats + ST1);
  // ---- InvResMLP block 0 ----
  k_gconv<<<BB * MM, 128, 0, stream>>>(cent, sel2, y1a, stats + ST1, g1, b1,
                                       stats + MO_PE, W_pe, g_pe, b_pe, W2a,
                                       y2a, stats + ST2A);
  k_conv_bnin<<<128, 256, 0, stream>>>(y2a, W2b, stats + ST2A, g2a, b2a, y2b,
                                       stats + ST2B, 64);
  // ---- InvResMLP block 1 (resid of block 0 fused into conv1) ----
  k_conv_resid<<<128, 256, 0, stream>>>(
      y1a, y2b, stats + ST1, g1, b1, stats + ST2B, g2b, b2b, W1 + CO * CO, y1b,
      stats + ST1 + SG * 256, 64);
  k_gconv<<<BB * MM, 128, 0, stream>>>(cent, sel2, y1b, stats + ST1 + SG * 256,
                                       g1 + 128, b1 + 128, stats + MO_PE, W_pe,
                                       g_pe, b_pe, W2a + CO * CO, y2a,
                                       stats + ST2A + SG * 256);
  k_conv_bnin<<<128, 256, 0, stream>>>(y2a, W2b + CO * CO,
                                       stats + ST2A + SG * 256, g2a + 128,
                                       b2a + 128, y2b, stats + ST2B + 256, 64);
  k_resid_fin<<<(BB * MM * CO) / 256, 256, 0, stream>>>(
      y1b, stats + ST1 + SG * 256, g1 + 128, b1 + 128, y2b,
      stats + ST2B + 256, g2b + 128, b2b + 128, xf);
}

// Round 11
// 2674.903 us; speedup vs baseline: 1.0460x; 1.0017x over previous
//
#include <hip/hip_runtime.h>

// StageBlocks: FPS -> ball-query -> conv/BN/max -> 2x InvResMLP on MI355X.
// Discrete decisions (FPS argmax, ball membership) use contract-off f32 to
// match XLA/np rounding bitwise. BN via sufficient statistics.
// R11: R10 + FPS centroids staged in LDS (24 KB) and dumped at the end.
// __syncthreads() drains vmcnt(0); R8's per-iter global store from t0 cost
// a store-ack (~200-400 cyc) at each barrier. Loop body now has ZERO vmem
// ops, so both barrier drains are lgkm-only. Tail unchanged from R10.

#define BB 4
#define NN 8192
#define MM 2048
#define KK 32
#define CI 64
#define CO 128
#define SG 16  // stat groups for high-block-count atomics

typedef float vf2 __attribute__((ext_vector_type(2)));

// stats layout (doubles)
#define ST_X 0
#define MO_PS 256
#define MO_PE 272
#define ST1 288                     // 2 x SG x 256 (block0, block1)
#define ST2A (288 + 2 * SG * 256)   // 2 x SG x 256
#define ST2B (ST2A + 2 * SG * 256)  // 2 x 256
#define ST_TOTAL (ST2B + 512)

__device__ __forceinline__ float sq3(float dx, float dy, float dz) {
#pragma clang fp contract(off)
  return dx * dx + dy * dy + dz * dz;  // ((x+y)+z), no FMA: matches XLA/np
}

__device__ __forceinline__ void fin_stats_d(const double* st, float gam,
                                            float bet, double cnt, int ch,
                                            float* sc, float* sh) {
  double mean = st[ch] / cnt;
  double var = st[128 + ch] / cnt - mean * mean;
  if (var < 0) var = 0;
  double s = (double)gam / sqrt(var + 1e-5);
  *sc = (float)s;
  *sh = (float)((double)bet - mean * s);
}

// grouped (SG partial sums) variant
__device__ __forceinline__ void fin_grp_d(const double* st, float gam,
                                          float bet, double cnt, int ch,
                                          float* sc, float* sh) {
  double sum = 0, ssq = 0;
#pragma unroll
  for (int g = 0; g < SG; g++) {
    sum += st[g * 256 + ch];
    ssq += st[g * 256 + 128 + ch];
  }
  double mean = sum / cnt;
  double var = ssq / cnt - mean * mean;
  if (var < 0) var = 0;
  double s = (double)gam / sqrt(var + 1e-5);
  *sc = (float)s;
  *sh = (float)((double)bet - mean * s);
}

__device__ __forceinline__ void fin_mom_d(const double* mo, const float* Wrow,
                                          float gam, float bet, double cnt,
                                          float* sc, float* sh) {
  double w0 = Wrow[0], w1 = Wrow[1], w2 = Wrow[2];
  double mx = mo[0] / cnt, my = mo[1] / cnt, mz = mo[2] / cnt;
  double sxx = mo[3] / cnt, sxy = mo[4] / cnt, sxz = mo[5] / cnt;
  double syy = mo[6] / cnt, syz = mo[7] / cnt, szz = mo[8] / cnt;
  double mean = w0 * mx + w1 * my + w2 * mz;
  double ey2 = w0 * w0 * sxx + w1 * w1 * syy + w2 * w2 * szz +
               2.0 * (w0 * w1 * sxy + w0 * w2 * sxz + w1 * w2 * syz);
  double var = ey2 - mean * mean;
  if (var < 0) var = 0;
  double s = (double)gam / sqrt(var + 1e-5);
  *sc = (float)s;
  *sh = (float)((double)bet - mean * s);
}

// ---------------- DPP helpers ----------------
template <int CTRL>
__device__ __forceinline__ int dpp_i(int v) {
  return __builtin_amdgcn_update_dpp(v, v, CTRL, 0xF, 0xF, false);
}
template <int CTRL>
__device__ __forceinline__ float dpp_f(float v) {
  return __int_as_float(dpp_i<CTRL>(__float_as_int(v)));
}

// ---------------- merged FPS (blocks 0..3) + conv_x (blocks 4..259) -------
#define FT 512
#define NP 8  // float2 pairs per thread = 16 points
#define NW 8

__global__ __launch_bounds__(FT) void k_fps_conv(
    const float* __restrict__ pos, const float* __restrict__ x,
    const float* __restrict__ W_x, float* __restrict__ cent,
    float* __restrict__ fpre, double* __restrict__ stats) {
  __shared__ alignas(16) float s_wv[NW];
  __shared__ alignas(16) int s_wi[NW];
  __shared__ alignas(16) float s_pts[NN * 3];   // 96 KB point table
  __shared__ alignas(16) float s_cent[MM * 3];  // 24 KB centroid staging
  int t = threadIdx.x;
  if (blockIdx.x >= BB) {
    // ---- conv part: 64->128 over BB*NN rows, 256 blocks x 512 threads ----
    int cb = blockIdx.x - BB;
    int o = t & 127, q = t >> 7;  // q wave-uniform
    float4 w[CI / 4];
    const float4* Wv = (const float4*)(W_x + (size_t)o * CI);
#pragma unroll
    for (int i = 0; i < CI / 4; i++) w[i] = Wv[i];
    int row0 = cb * 128;
    float ssum = 0.f, ssq = 0.f;
    for (int r = 0; r < 128; r += 4) {
      int row = __builtin_amdgcn_readfirstlane(row0 + r + q);
      const float* xr = x + (size_t)row * CI;
      float acc = 0.f;
#pragma unroll
      for (int i = 0; i < CI / 4; i++) {
        float4 a = *(const float4*)(xr + 4 * i);
        acc += a.x * w[i].x + a.y * w[i].y + a.z * w[i].z + a.w * w[i].w;
      }
      fpre[(size_t)row * CO + o] = acc;
      ssum += acc;
      ssq += acc * acc;
    }
    atomicAdd(&stats[ST_X + o], (double)ssum);
    atomicAdd(&stats[ST_X + 128 + o], (double)ssq);
    return;
  }
  // ---- FPS part: two-phase argmax, pk slot loop, LDS tables ----
  int b = blockIdx.x;
  const float* P = pos + (size_t)b * NN * 3;
  float* C = cent + (size_t)b * MM * 3;
  int lane = t & 63, w = t >> 6;
  for (int i = t; i < (NN * 3) / 4; i += FT) {
    ((float4*)s_pts)[i] = ((const float4*)P)[i];
  }
  vf2 px[NP], py[NP], pz[NP], ds[NP];
#pragma unroll
  for (int s = 0; s < NP; s++) {
    int ia = (2 * s) * FT + t;
    int ib = ia + FT;
    px[s] = (vf2){P[ia * 3 + 0], P[ib * 3 + 0]};
    py[s] = (vf2){P[ia * 3 + 1], P[ib * 3 + 1]};
    pz[s] = (vf2){P[ia * 3 + 2], P[ib * 3 + 2]};
    ds[s] = (vf2){1e10f, 1e10f};
  }
  float lx = P[0], ly = P[1], lz = P[2];
  if (t == 0) {
    s_cent[0] = lx;
    s_cent[1] = ly;
    s_cent[2] = lz;
  }
  __syncthreads();  // tables ready
  for (int m = 1; m < MM; m++) {
    vf2 l2x = (vf2){lx, lx}, l2y = (vf2){ly, ly}, l2z = (vf2){lz, lz};
    vf2 bmax = (vf2){-1.0f, -1.0f};
    {
#pragma clang fp contract(off)
#pragma unroll
      for (int s = 0; s < NP; s++) {
        vf2 dx = px[s] - l2x;
        vf2 dy = py[s] - l2y;
        vf2 dz = pz[s] - l2z;
        vf2 d2 = dx * dx + dy * dy + dz * dz;  // per-lane IEEE, no FMA
        vf2 nd = __builtin_elementwise_min(ds[s], d2);
        ds[s] = nd;
        bmax = __builtin_elementwise_max(bmax, nd);
      }
    }
    float bv = fmaxf(bmax.x, bmax.y);
    bv = fmaxf(bv, dpp_f<0x111>(bv));
    bv = fmaxf(bv, dpp_f<0x112>(bv));
    bv = fmaxf(bv, dpp_f<0x114>(bv));
    bv = fmaxf(bv, dpp_f<0x118>(bv));
    bv = fmaxf(bv, dpp_f<0x142>(bv));
    bv = fmaxf(bv, dpp_f<0x143>(bv));
    if (lane == 63) s_wv[w] = bv;
    float gw63 =
        __int_as_float(__builtin_amdgcn_readlane(__float_as_int(bv), 63));
    __syncthreads();
    float4 va = ((const float4*)s_wv)[0];
    float4 vb = ((const float4*)s_wv)[1];
    float gmax = fmaxf(fmaxf(fmaxf(va.x, va.y), fmaxf(va.z, va.w)),
                       fmaxf(fmaxf(vb.x, vb.y), fmaxf(vb.z, vb.w)));
    int bi = 0x7fffffff;
    if (gw63 == gmax) {  // non-winner waves: ds <= bv < gmax, skip scan
#pragma unroll
      for (int s = 0; s < NP; s++) {
        int ia = (2 * s) * FT + t;
        int ib2 = ia + FT;
        bi = (ds[s].x == gmax) ? (ia < bi ? ia : bi) : bi;
        bi = (ds[s].y == gmax) ? (ib2 < bi ? ib2 : bi) : bi;
      }
      int u;
      u = dpp_i<0x111>(bi); bi = u < bi ? u : bi;
      u = dpp_i<0x112>(bi); bi = u < bi ? u : bi;
      u = dpp_i<0x114>(bi); bi = u < bi ? u : bi;
      u = dpp_i<0x118>(bi); bi = u < bi ? u : bi;
      u = dpp_i<0x142>(bi); bi = u < bi ? u : bi;
      u = dpp_i<0x143>(bi); bi = u < bi ? u : bi;
    }
    if (lane == 63) s_wi[w] = bi;
    __syncthreads();
    int4 ia4 = ((const int4*)s_wi)[0];
    int4 ib4 = ((const int4*)s_wi)[1];
    int g0 = ia4.x < ia4.y ? ia4.x : ia4.y;
    int g1 = ia4.z < ia4.w ? ia4.z : ia4.w;
    int g2 = ib4.x < ib4.y ? ib4.x : ib4.y;
    int g3 = ib4.z < ib4.w ? ib4.z : ib4.w;
    g0 = g0 < g1 ? g0 : g1;
    g2 = g2 < g3 ? g2 : g3;
    int gidx = g0 < g2 ? g0 : g2;
    lx = s_pts[gidx * 3 + 0];
    ly = s_pts[gidx * 3 + 1];
    lz = s_pts[gidx * 3 + 2];
    if (t == 0) {
      s_cent[m * 3 + 0] = lx;
      s_cent[m * 3 + 1] = ly;
      s_cent[m * 3 + 2] = lz;
    }
  }
  __syncthreads();
  for (int i = t; i < (MM * 3) / 4; i += FT) {
    ((float4*)C)[i] = ((const float4*)s_cent)[i];
  }
}

// ---------------- both ball queries in one kernel (4 chunks/iter) --------
__global__ __launch_bounds__(256) void k_bq2(const float* __restrict__ pos,
                                             const float* __restrict__ cent,
                                             int* __restrict__ sel1,
                                             int* __restrict__ sel2,
                                             double* __restrict__ stats) {
  int lane = threadIdx.x & 63, w = threadIdx.x >> 6;
  const float* pts;
  int npts, pair;
  float rsq, inv_r;
  int* sel;
  double* mom;
  int half = (BB * MM) / 4;
  if (blockIdx.x < half) {
    pts = pos; npts = NN; rsq = 0.01f; inv_r = 10.0f;
    sel = sel1; mom = stats + MO_PS;
    pair = blockIdx.x * 4 + w;
  } else {
    pts = cent; npts = MM; rsq = 0.04f; inv_r = 5.0f;
    sel = sel2; mom = stats + MO_PE;
    pair = (blockIdx.x - half) * 4 + w;
  }
  int b = pair / MM;
  const float* P = pts + (size_t)b * npts * 3;
  const float* C = cent + (size_t)pair * 3;
  float cx = C[0], cy = C[1], cz = C[2];
  __shared__ int s_sel[4][KK];
  __shared__ float s_mom[4][9];
  int cnt = 0;
  unsigned long long ltm = (1ull << lane) - 1ull;
  int nit = npts >> 8;  // 256 points per iteration
  for (int ch = 0; ch < nit; ch++) {
    int i0 = (ch << 8) + lane;
    bool h0, h1, h2, h3;
    {
      float a0 = P[i0 * 3 + 0], a1 = P[i0 * 3 + 1], a2 = P[i0 * 3 + 2];
      float b0 = P[(i0 + 64) * 3 + 0], b1 = P[(i0 + 64) * 3 + 1],
            b2 = P[(i0 + 64) * 3 + 2];
      float c0 = P[(i0 + 128) * 3 + 0], c1 = P[(i0 + 128) * 3 + 1],
            c2 = P[(i0 + 128) * 3 + 2];
      float e0 = P[(i0 + 192) * 3 + 0], e1 = P[(i0 + 192) * 3 + 1],
            e2 = P[(i0 + 192) * 3 + 2];
      h0 = sq3(a0 - cx, a1 - cy, a2 - cz) < rsq;
      h1 = sq3(b0 - cx, b1 - cy, b2 - cz) < rsq;
      h2 = sq3(c0 - cx, c1 - cy, c2 - cz) < rsq;
      h3 = sq3(e0 - cx, e1 - cy, e2 - cz) < rsq;
    }
    unsigned long long m0 = __ballot(h0);
    unsigned long long m1 = __ballot(h1);
    unsigned long long m2 = __ballot(h2);
    unsigned long long m3 = __ballot(h3);
    if (m0) {
      int k = cnt + __popcll(m0 & ltm);
      if (h0 && k < KK) s_sel[w][k] = i0;
      cnt += __popcll(m0);
    }
    if (m1) {
      int k = cnt + __popcll(m1 & ltm);
      if (h1 && k < KK) s_sel[w][k] = i0 + 64;
      cnt += __popcll(m1);
    }
    if (m2) {
      int k = cnt + __popcll(m2 & ltm);
      if (h2 && k < KK) s_sel[w][k] = i0 + 128;
      cnt += __popcll(m2);
    }
    if (m3) {
      int k = cnt + __popcll(m3 & ltm);
      if (h3 && k < KK) s_sel[w][k] = i0 + 192;
      cnt += __popcll(m3);
    }
    if (cnt >= KK) break;
  }
  int total = cnt < KK ? cnt : KK;
  int myidx = 0;
  if (lane < KK) {
    int v = (lane < total) ? s_sel[w][lane] : s_sel[w][0];
    sel[(size_t)pair * KK + lane] = v;
    myidx = v;
  }
  float gx = 0.f, gy = 0.f, gz = 0.f;
  if (lane < KK) {
    gx = (P[myidx * 3 + 0] - cx) * inv_r;
    gy = (P[myidx * 3 + 1] - cy) * inv_r;
    gz = (P[myidx * 3 + 2] - cz) * inv_r;
  }
  float v9[9] = {gx, gy, gz, gx * gx, gx * gy, gx * gz, gy * gy, gy * gz, gz * gz};
#pragma unroll
  for (int j = 0; j < 9; j++) {
#pragma unroll
    for (int off = 32; off > 0; off >>= 1) v9[j] += __shfl_xor(v9[j], off);
  }
  if (lane == 0) {
#pragma unroll
    for (int j = 0; j < 9; j++) s_mom[w][j] = v9[j];
  }
  __syncthreads();
  if (threadIdx.x < 9) {
    double a = (double)s_mom[0][threadIdx.x] + s_mom[1][threadIdx.x] +
               s_mom[2][threadIdx.x] + s_mom[3][threadIdx.x];
    atomicAdd(&mom[threadIdx.x], a);
  }
}

// ---------------- fused stage-1 aggregation + conv1(block0) -------------
__global__ __launch_bounds__(128) void k_xf_conv1(
    const float* __restrict__ pos, const float* __restrict__ cent,
    const int* __restrict__ sel1, const float* __restrict__ fpre,
    const float* __restrict__ Wps, const float* __restrict__ g_ps,
    const float* __restrict__ b_ps, const float* __restrict__ g_x,
    const float* __restrict__ b_x, const double* __restrict__ stats,
    const float* __restrict__ W1, float* __restrict__ y1a,
    double* __restrict__ st1out) {
  int pair = blockIdx.x;
  int b = pair >> 11;
  int o = threadIdx.x;
  float sx, hx, sp, hp;
  fin_stats_d(stats + ST_X, g_x[o], b_x[o], (double)(BB * NN), o, &sx, &hx);
  fin_mom_d(stats + MO_PS, Wps + o * 3, g_ps[o], b_ps[o],
            (double)(BB * MM * KK), &sp, &hp);
  float w0 = Wps[o * 3 + 0], w1 = Wps[o * 3 + 1], w2 = Wps[o * 3 + 2];
  const float* C = cent + (size_t)pair * 3;
  float cx = C[0], cy = C[1], cz = C[2];
  const float* P = pos + (size_t)b * NN * 3;
  const float* F = fpre + (size_t)b * NN * CO;
  __shared__ int s_idx[KK];
  __shared__ float s_xf[128];
  if (o < KK) s_idx[o] = sel1[(size_t)pair * KK + o];
  __syncthreads();
  float acc = -1e30f;
#pragma unroll 4
  for (int k = 0; k < KK; k++) {
    int idx = __builtin_amdgcn_readfirstlane(s_idx[k]);
    float gx = (P[idx * 3 + 0] - cx) * 10.0f;
    float gy = (P[idx * 3 + 1] - cy) * 10.0f;
    float gz = (P[idx * 3 + 2] - cz) * 10.0f;
    float y = fmaxf((w0 * gx + w1 * gy + w2 * gz) * sp + hp, 0.f);
    float f = fmaxf(F[(size_t)idx * CO + o] * sx + hx, 0.f);
    float v = y + f;
    acc = v > acc ? v : acc;
  }
  s_xf[o] = acc;
  __syncthreads();
  const float4* Wv = (const float4*)(W1 + (size_t)o * CO);
  const float4* gv = (const float4*)s_xf;
  float dot = 0.f;
#pragma unroll
  for (int i = 0; i < CO / 4; i++) {
    float4 a = gv[i];
    float4 ww = Wv[i];
    dot += a.x * ww.x + a.y * ww.y + a.z * ww.z + a.w * ww.w;
  }
  y1a[(size_t)pair * CO + o] = dot;
  int grp = pair & (SG - 1);
  atomicAdd(&st1out[grp * 256 + o], (double)dot);
  atomicAdd(&st1out[grp * 256 + 128 + o], (double)(dot * dot));
}

// ---------------- conv with relu(bn(in)) input, scales from grouped stats -
__global__ __launch_bounds__(256) void k_conv_bnin(
    const float* __restrict__ in, const float* __restrict__ W,
    const double* __restrict__ st_grp, const float* __restrict__ gam,
    const float* __restrict__ bet, float* __restrict__ out,
    double* __restrict__ stats, int rows_per_block) {
  __shared__ float s_sc[128], s_sh[128];
  int t = threadIdx.x;
  if (t < 128) {
    fin_grp_d(st_grp, gam[t], bet[t], (double)(BB * MM), t, &s_sc[t],
              &s_sh[t]);
  }
  __syncthreads();
  int o = t & 127, half = t >> 7;
  float4 w[CO / 4];
  const float4* Wv = (const float4*)(W + (size_t)o * CO);
#pragma unroll
  for (int i = 0; i < CO / 4; i++) w[i] = Wv[i];
  int row0 = blockIdx.x * rows_per_block;
  float ssum = 0.f, ssq = 0.f;
  for (int r = 0; r < rows_per_block; r += 2) {
    int row = __builtin_amdgcn_readfirstlane(row0 + r + half);
    const float* xr = in + (size_t)row * CO;
    float acc = 0.f;
#pragma unroll
    for (int i = 0; i < CO / 4; i++) {
      float4 a = *(const float4*)(xr + 4 * i);
      a.x = fmaxf(a.x * s_sc[4 * i + 0] + s_sh[4 * i + 0], 0.f);
      a.y = fmaxf(a.y * s_sc[4 * i + 1] + s_sh[4 * i + 1], 0.f);
      a.z = fmaxf(a.z * s_sc[4 * i + 2] + s_sh[4 * i + 2], 0.f);
      a.w = fmaxf(a.w * s_sc[4 * i + 3] + s_sh[4 * i + 3], 0.f);
      acc += a.x * w[i].x + a.y * w[i].y + a.z * w[i].z + a.w * w[i].w;
    }
    out[(size_t)row * CO + o] = acc;
    ssum += acc;
    ssq += acc * acc;
  }
  atomicAdd(&stats[o], (double)ssum);
  atomicAdd(&stats[128 + o], (double)ssq);
}

// ---------------- conv1 of block 1 with resid-of-block-0 fused input -----
__global__ __launch_bounds__(256) void k_conv_resid(
    const float* __restrict__ y1prev, const float* __restrict__ y2bprev,
    const double* __restrict__ st1p, const float* __restrict__ g1p,
    const float* __restrict__ b1p, const double* __restrict__ st2bp,
    const float* __restrict__ g2bp, const float* __restrict__ b2bp,
    const float* __restrict__ W, float* __restrict__ y1out,
    double* __restrict__ stats, int rows_per_block) {
  __shared__ float s_s1[128], s_h1[128], s_s2[128], s_h2[128];
  int t = threadIdx.x;
  if (t < 128) {
    fin_grp_d(st1p, g1p[t], b1p[t], (double)(BB * MM), t, &s_s1[t], &s_h1[t]);
    fin_stats_d(st2bp, g2bp[t], b2bp[t], (double)(BB * MM), t, &s_s2[t],
                &s_h2[t]);
  }
  __syncthreads();
  int o = t & 127, half = t >> 7;
  float4 w[CO / 4];
  const float4* Wv = (const float4*)(W + (size_t)o * CO);
#pragma unroll
  for (int i = 0; i < CO / 4; i++) w[i] = Wv[i];
  int row0 = blockIdx.x * rows_per_block;
  float ssum = 0.f, ssq = 0.f;
  for (int r = 0; r < rows_per_block; r += 2) {
    int row = __builtin_amdgcn_readfirstlane(row0 + r + half);
    const float* ar = y1prev + (size_t)row * CO;
    const float* br = y2bprev + (size_t)row * CO;
    float acc = 0.f;
#pragma unroll
    for (int i = 0; i < CO / 4; i++) {
      float4 a = *(const float4*)(ar + 4 * i);
      float4 bb = *(const float4*)(br + 4 * i);
      float x0 = fmaxf(fmaxf(a.x * s_s1[4 * i + 0] + s_h1[4 * i + 0], 0.f) +
                           (bb.x * s_s2[4 * i + 0] + s_h2[4 * i + 0]), 0.f);
      float x1 = fmaxf(fmaxf(a.y * s_s1[4 * i + 1] + s_h1[4 * i + 1], 0.f) +
                           (bb.y * s_s2[4 * i + 1] + s_h2[4 * i + 1]), 0.f);
      float x2 = fmaxf(fmaxf(a.z * s_s1[4 * i + 2] + s_h1[4 * i + 2], 0.f) +
                           (bb.z * s_s2[4 * i + 2] + s_h2[4 * i + 2]), 0.f);
      float x3 = fmaxf(fmaxf(a.w * s_s1[4 * i + 3] + s_h1[4 * i + 3], 0.f) +
                           (bb.w * s_s2[4 * i + 3] + s_h2[4 * i + 3]), 0.f);
      acc += x0 * w[i].x + x1 * w[i].y + x2 * w[i].z + x3 * w[i].w;
    }
    y1out[(size_t)row * CO + o] = acc;
    ssum += acc;
    ssq += acc * acc;
  }
  int grp = blockIdx.x & (SG - 1);
  atomicAdd(&stats[grp * 256 + o], (double)ssum);
  atomicAdd(&stats[grp * 256 + 128 + o], (double)ssq);
}

// ---------------- fused: g = max_k(relu(bn1(y1[sel2])) + pe); y2a = W2a*g -
__global__ __launch_bounds__(128) void k_gconv(
    const float* __restrict__ cent, const int* __restrict__ sel2,
    const float* __restrict__ y1in, const double* __restrict__ st1,
    const float* __restrict__ g1v, const float* __restrict__ b1v,
    const double* __restrict__ mo_pe, const float* __restrict__ Wpe,
    const float* __restrict__ gpe, const float* __restrict__ bpe,
    const float* __restrict__ W2a, float* __restrict__ y2a,
    double* __restrict__ st2a) {
  int pair = blockIdx.x;
  int b = pair >> 11;
  int o = threadIdx.x;
  float s1, h1, se, he;
  fin_grp_d(st1, g1v[o], b1v[o], (double)(BB * MM), o, &s1, &h1);
  fin_mom_d(mo_pe, Wpe + o * 3, gpe[o], bpe[o], (double)(BB * MM * KK), &se,
            &he);
  float w0 = Wpe[o * 3 + 0], w1 = Wpe[o * 3 + 1], w2 = Wpe[o * 3 + 2];
  const float* C = cent + (size_t)pair * 3;
  float cx = C[0], cy = C[1], cz = C[2];
  const float* CB = cent + (size_t)b * MM * 3;
  const float* Y = y1in + (size_t)b * MM * CO;
  __shared__ int s_idx[KK];
  __shared__ float s_g[128];
  if (o < KK) s_idx[o] = sel2[(size_t)pair * KK + o];
  __syncthreads();
  float acc = -1e30f;
#pragma unroll 4
  for (int k = 0; k < KK; k++) {
    int idx = __builtin_amdgcn_readfirstlane(s_idx[k]);
    float gx = (CB[idx * 3 + 0] - cx) * 5.0f;
    float gy = (CB[idx * 3 + 1] - cy) * 5.0f;
    float gz = (CB[idx * 3 + 2] - cz) * 5.0f;
    float pe = fmaxf((w0 * gx + w1 * gy + w2 * gz) * se + he, 0.f);
    float f = fmaxf(Y[(size_t)idx * CO + o] * s1 + h1, 0.f);
    float v = pe + f;
    acc = v > acc ? v : acc;
  }
  s_g[o] = acc;
  __syncthreads();
  const float4* Wv = (const float4*)(W2a + (size_t)o * CO);
  const float4* gv = (const float4*)s_g;
  float dot = 0.f;
#pragma unroll
  for (int i = 0; i < CO / 4; i++) {
    float4 a = gv[i];
    float4 ww = Wv[i];
    dot += a.x * ww.x + a.y * ww.y + a.z * ww.z + a.w * ww.w;
  }
  y2a[(size_t)pair * CO + o] = dot;
  int grp = pair & (SG - 1);
  atomicAdd(&st2a[grp * 256 + o], (double)dot);
  atomicAdd(&st2a[grp * 256 + 128 + o], (double)(dot * dot));
}

// ---------------- final residual (fin folded per-thread) ----------------
__global__ __launch_bounds__(256) void k_resid_fin(
    const float* __restrict__ y1b, const double* __restrict__ st1,
    const float* __restrict__ g1v, const float* __restrict__ b1v,
    const float* __restrict__ y2b, const double* __restrict__ st2b,
    const float* __restrict__ g2bv, const float* __restrict__ b2bv,
    float* __restrict__ xf) {
  int i = blockIdx.x * 256 + threadIdx.x;
  int o = i & 127;
  float s1, h1, s2, h2;
  fin_grp_d(st1, g1v[o], b1v[o], (double)(BB * MM), o, &s1, &h1);
  fin_stats_d(st2b, g2bv[o], b2bv[o], (double)(BB * MM), o, &s2, &h2);
  float f = fmaxf(y1b[i] * s1 + h1, 0.f);
  float v = y2b[i] * s2 + h2;
  xf[i] = fmaxf(f + v, 0.f);
}

extern "C" void kernel_launch(void* const* d_in, const int* in_sizes, int n_in,
                              void* d_out, int out_size, void* d_ws,
                              size_t ws_size, hipStream_t stream) {
  const float* pos = (const float*)d_in[0];
  const float* x = (const float*)d_in[1];
  const float* W_x = (const float*)d_in[2];
  const float* g_x = (const float*)d_in[3];
  const float* b_x = (const float*)d_in[4];
  const float* W_ps = (const float*)d_in[5];
  const float* g_ps = (const float*)d_in[6];
  const float* b_ps = (const float*)d_in[7];
  const float* W_pe = (const float*)d_in[8];
  const float* g_pe = (const float*)d_in[9];
  const float* b_pe = (const float*)d_in[10];
  const float* W1 = (const float*)d_in[11];
  const float* g1 = (const float*)d_in[12];
  const float* b1 = (const float*)d_in[13];
  const float* W2a = (const float*)d_in[14];
  const float* g2a = (const float*)d_in[15];
  const float* b2a = (const float*)d_in[16];
  const float* W2b = (const float*)d_in[17];
  const float* g2b = (const float*)d_in[18];
  const float* b2b = (const float*)d_in[19];

  float* cent = (float*)d_out;             // (B,M,3)
  float* xf = cent + (size_t)BB * MM * 3;  // (B,M,128)

  char* p = (char*)d_ws;
  double* stats = (double*)p; p += (size_t)ST_TOTAL * sizeof(double);
  int* sel1 = (int*)p;        p += (size_t)BB * MM * KK * sizeof(int);
  int* sel2 = (int*)p;        p += (size_t)BB * MM * KK * sizeof(int);
  float* fpre = (float*)p;    p += (size_t)BB * NN * CO * sizeof(float);
  float* y1a = (float*)p;     p += (size_t)BB * MM * CO * sizeof(float);
  float* y1b = (float*)p;     p += (size_t)BB * MM * CO * sizeof(float);
  float* y2a = (float*)p;     p += (size_t)BB * MM * CO * sizeof(float);
  float* y2b = (float*)p;     p += (size_t)BB * MM * CO * sizeof(float);

  hipMemsetAsync(stats, 0, (size_t)ST_TOTAL * sizeof(double), stream);
  k_fps_conv<<<BB + 256, FT, 0, stream>>>(pos, x, W_x, cent, fpre, stats);
  k_bq2<<<(BB * MM) / 2, 256, 0, stream>>>(pos, cent, sel1, sel2, stats);
  k_xf_conv1<<<BB * MM, 128, 0, stream>>>(pos, cent, sel1, fpre, W_ps, g_ps,
                                          b_ps, g_x, b_x, stats, W1, y1a,
                                          stats + ST1);
  // ---- InvResMLP block 0 ----
  k_gconv<<<BB * MM, 128, 0, stream>>>(cent, sel2, y1a, stats + ST1, g1, b1,
                                       stats + MO_PE, W_pe, g_pe, b_pe, W2a,
                                       y2a, stats + ST2A);
  k_conv_bnin<<<128, 256, 0, stream>>>(y2a, W2b, stats + ST2A, g2a, b2a, y2b,
                                       stats + ST2B, 64);
  // ---- InvResMLP block 1 (resid of block 0 fused into conv1) ----
  k_conv_resid<<<128, 256, 0, stream>>>(
      y1a, y2b, stats + ST1, g1, b1, stats + ST2B, g2b, b2b, W1 + CO * CO, y1b,
      stats + ST1 + SG * 256, 64);
  k_gconv<<<BB * MM, 128, 0, stream>>>(cent, sel2, y1b, stats + ST1 + SG * 256,
                                       g1 + 128, b1 + 128, stats + MO_PE, W_pe,
                                       g_pe, b_pe, W2a + CO * CO, y2a,
                                       stats + ST2A + SG * 256);
  k_conv_bnin<<<128, 256, 0, stream>>>(y2a, W2b + CO * CO,
                                       stats + ST2A + SG * 256, g2a + 128,
                                       b2a + 128, y2b, stats + ST2B + 256, 64);
  k_resid_fin<<<(BB * MM * CO) / 256, 256, 0, stream>>>(
      y1b, stats + ST1 + SG * 256, g1 + 128, b1 + 128, y2b,
      stats + ST2B + 256, g2b + 128, b2b + 128, xf);
}